// Round 1
// baseline (85.882 us; speedup 1.0000x reference)
//
#include <hip/hip_runtime.h>
#include <cstdint>

// Quantum circuit simulator, restructured:
//  - SWAP(anc,rec) = wire relabeling => only 14 physical bits ever used;
//    layer L uses physical anc bits {8+2L, 9+2L} for H/CRZ/CCRX-controls.
//  - During layer L, earlier anc bits are untouched spectators and current
//    anc bits start |0>, so the state factors into independent 1024-amp
//    chunks: 16 (L0), 64 (L1), 256 (L2). One wave (64 lanes) per chunk,
//    16 amps/lane, 4-bit local bit-groups, LDS (8KB) between regroupings.
//  - Gate fusion: CRZ block = one phase multiply; RZZ*RYY*RXX = diag+antidiag
//    4x4 (alpha,beta,gamma,delta); layer tail Rx,Ry,Rz fused into next
//    layer's rot(x) (U_pre) / final U_post; initial H fused into layer-0
//    product-state construction.

struct F2 { float x, y; };

__device__ __forceinline__ F2 cmul(F2 a, F2 b) {
  return F2{ a.x * b.x - a.y * b.y, a.x * b.y + a.y * b.x };
}
__device__ __forceinline__ F2 cfma2(F2 a, F2 b, F2 c) { // a*b + c
  return F2{ fmaf(a.x, b.x, fmaf(-a.y, b.y, c.x)),
             fmaf(a.x, b.y, fmaf( a.y, b.x, c.y)) };
}

// deposit bits of x into the set positions of compile-time MASK (low->high)
template<uint32_t MASK>
__device__ __forceinline__ uint32_t pdep10(uint32_t x) {
  uint32_t r = 0;
  #pragma unroll
  for (int b = 0; b < 10; ++b) {
    if (MASK & (1u << b)) { r |= (x & 1u) << b; x >>= 1; }
  }
  return r;
}

// LDS anti-bank-conflict swizzle: uniform 4 lanes per bank-pair in all passes
__device__ __forceinline__ uint32_t sw(uint32_t i) { return i ^ ((i >> 5) & 31u); }

template<uint32_t MASK>
__device__ __forceinline__ void readGrp(const F2* lds, int lane, F2 a[16]) {
  const uint32_t base = pdep10<(~MASK) & 0x3FFu>((uint32_t)lane);
  #pragma unroll
  for (uint32_t j = 0; j < 16; ++j) a[j] = lds[sw(base | pdep10<MASK>(j))];
}
template<uint32_t MASK>
__device__ __forceinline__ void writeGrp(F2* lds, int lane, const F2 a[16]) {
  const uint32_t base = pdep10<(~MASK) & 0x3FFu>((uint32_t)lane);
  #pragma unroll
  for (uint32_t j = 0; j < 16; ++j) lds[sw(base | pdep10<MASK>(j))] = a[j];
}

// single-qubit 2x2 on local bit p; U = {u00,u01,u10,u11}
__device__ __forceinline__ void gate1(F2 a[16], const F2 U[4], int p) {
  const int s = 1 << p;
  #pragma unroll
  for (int i = 0; i < 16; ++i) {
    if (i & s) continue;
    F2 a0 = a[i], a1 = a[i | s];
    a[i]     = cfma2(U[0], a0, cmul(U[1], a1));
    a[i | s] = cfma2(U[2], a0, cmul(U[3], a1));
  }
}

__device__ __forceinline__ void gateH(F2 a[16], int p) {
  const float R = 0.70710678118654752f;
  const int s = 1 << p;
  #pragma unroll
  for (int i = 0; i < 16; ++i) {
    if (i & s) continue;
    F2 a0 = a[i], a1 = a[i | s];
    a[i]     = F2{ (a0.x + a1.x) * R, (a0.y + a1.y) * R };
    a[i | s] = F2{ (a0.x - a1.x) * R, (a0.y - a1.y) * R };
  }
}

// fused RZZ*RYY*RXX: m = {alpha,beta,gamma,delta}; matrix index = b_p*2 + b_q
// out0 = a*v0 + g*v3 ; out3 = g*v0 + a*v3 ; out1 = b*v1 + d*v2 ; out2 = d*v1 + b*v2
__device__ __forceinline__ void gateM4(F2 a[16], const F2 m[4], int p, int q) {
  const int sp = 1 << p, sq = 1 << q;
  #pragma unroll
  for (int i = 0; i < 16; ++i) {
    if (i & (sp | sq)) continue;
    F2 v0 = a[i], v1 = a[i | sq], v2 = a[i | sp], v3 = a[i | sp | sq];
    a[i]           = cfma2(m[0], v0, cmul(m[2], v3));
    a[i | sp | sq] = cfma2(m[2], v0, cmul(m[0], v3));
    a[i | sq]      = cfma2(m[1], v1, cmul(m[3], v2));
    a[i | sp]      = cfma2(m[3], v1, cmul(m[1], v2));
  }
}

// doubly-controlled RX(pi/4): controls local bits c1,c2; target t
__device__ __forceinline__ void gateCCRX(F2 a[16], int c1, int c2, int t) {
  const float C = 0.92387953251128674f;  // cos(pi/8)
  const float S = 0.38268343236508978f;  // sin(pi/8)
  const int cm = (1 << c1) | (1 << c2);
  const int st = 1 << t;
  #pragma unroll
  for (int i = 0; i < 16; ++i) {
    if ((i & (cm | st)) != cm) continue;
    F2 a0 = a[i], a1 = a[i | st];
    // a0' = C a0 - i S a1 ; a1' = -i S a0 + C a1
    a[i]      = F2{ fmaf(C, a0.x,  S * a1.y), fmaf(C, a0.y, -S * a1.x) };
    a[i | st] = F2{ fmaf(C, a1.x,  S * a0.y), fmaf(C, a1.y, -S * a0.x) };
  }
}

__device__ __forceinline__ void rot_rx(F2 m[4], float t) {
  float c, s; __sincosf(0.5f * t, &s, &c);
  m[0] = F2{c, 0.f}; m[1] = F2{0.f, -s}; m[2] = F2{0.f, -s}; m[3] = F2{c, 0.f};
}
__device__ __forceinline__ void rot_ry(F2 m[4], float t) {
  float c, s; __sincosf(0.5f * t, &s, &c);
  m[0] = F2{c, 0.f}; m[1] = F2{-s, 0.f}; m[2] = F2{s, 0.f}; m[3] = F2{c, 0.f};
}
__device__ __forceinline__ void rot_rz(F2 m[4], float t) {
  float c, s; __sincosf(0.5f * t, &s, &c);
  m[0] = F2{c, -s}; m[1] = F2{0.f, 0.f}; m[2] = F2{0.f, 0.f}; m[3] = F2{c, s};
}
__device__ __forceinline__ void mat2mul(F2 o[4], const F2 A[4], const F2 B[4]) {
  o[0] = cfma2(A[0], B[0], cmul(A[1], B[2]));
  o[1] = cfma2(A[0], B[1], cmul(A[1], B[3]));
  o[2] = cfma2(A[2], B[0], cmul(A[3], B[2]));
  o[3] = cfma2(A[2], B[1], cmul(A[3], B[3]));
}

template<int L>
__global__ __launch_bounds__(64)
void qsim(const float* __restrict__ x, const float* __restrict__ w,
          const float* __restrict__ pwg, const F2* __restrict__ src,
          F2* __restrict__ dst, float* __restrict__ out)
{
  __shared__ F2 amp[1024];
  __shared__ F2 sUpre[8][4];
  __shared__ F2 sUpost[8][4];
  __shared__ F2 sM4[7][4];
  __shared__ float sPW[2][8];

  const int lane  = threadIdx.x;
  const int chunk = blockIdx.x;
  const int b = chunk >> (2 * L);
  const int s = chunk & ((1 << (2 * L)) - 1);

  if (L == 0 && blockIdx.x == 0) { out[lane] = 0.f; out[lane + 64] = 0.f; }

  // ---- per-chunk gate parameters (lane-parallel) ----
  if (lane < 8) {
    const int q = lane;
    F2 tail[4];
    if constexpr (L == 0) {
      const float R = 0.70710678118654752f;
      tail[0] = F2{R, 0.f}; tail[1] = F2{R, 0.f};
      tail[2] = F2{R, 0.f}; tail[3] = F2{-R, 0.f};
    } else {
      F2 rx[4], ry[4], rz[4], t0[4];
      rot_rx(rx, w[(L - 1) * 48 + 24 + 3 * q]);
      rot_ry(ry, w[(L - 1) * 48 + 24 + 3 * q + 1]);
      rot_rz(rz, w[(L - 1) * 48 + 24 + 3 * q + 2]);
      mat2mul(t0, ry, rx);
      mat2mul(tail, rz, t0);
    }
    F2 rot[4];
    if ((L & 1) == 0) rot_ry(rot, x[b * 8 + q]); else rot_rx(rot, x[b * 8 + q]);
    F2 u[4]; mat2mul(u, rot, tail);
    #pragma unroll
    for (int k = 0; k < 4; ++k) sUpre[q][k] = u[k];
  } else if (L == 2 && lane >= 8 && lane < 16) {
    const int q = lane - 8;
    F2 rx[4], ry[4], rz[4], t0[4], t1[4];
    rot_rx(rx, w[2 * 48 + 24 + 3 * q]);
    rot_ry(ry, w[2 * 48 + 24 + 3 * q + 1]);
    rot_rz(rz, w[2 * 48 + 24 + 3 * q + 2]);
    mat2mul(t0, ry, rx); mat2mul(t1, rz, t0);
    #pragma unroll
    for (int k = 0; k < 4; ++k) sUpost[q][k] = t1[k];
  } else if (lane >= 16 && lane < 23) {
    const int p = lane - 16;
    float cx, sx, cy, sy, cz, sz;
    __sincosf(0.5f * w[L * 48 + 3 * p    ], &sx, &cx);
    __sincosf(0.5f * w[L * 48 + 3 * p + 1], &sy, &cy);
    __sincosf(0.5f * w[L * 48 + 3 * p + 2], &sz, &cz);
    const F2 e  = F2{cz, -sz};
    const F2 eb = F2{cz,  sz};
    const float P = cx * cy + sx * sy, Q = cx * cy - sx * sy;
    sM4[p][0] = F2{ e.x * P,  e.y * P };                    // alpha
    sM4[p][1] = F2{ eb.x * Q, eb.y * Q };                   // beta
    sM4[p][2] = cmul(e,  F2{0.f,  sy * cx - sx * cy});      // gamma
    sM4[p][3] = cmul(eb, F2{0.f, -(sx * cy + sy * cx)});    // delta
  } else if (lane >= 24 && lane < 32) {
    const int j = lane - 24;
    sPW[0][j] = pwg[L * 16 + j];
    sPW[1][j] = pwg[L * 16 + 8 + j];
  }
  __syncthreads();

  F2 a[16];

  if constexpr (L == 0) {
    // initial product state directly in P3 grouping {0,1,8,9}
    F2 lf = F2{1.f, 0.f};
    #pragma unroll
    for (int t = 0; t < 6; ++t) {
      const int bit = (lane >> t) & 1;
      F2 col = bit ? sUpre[2 + t][2] : sUpre[2 + t][0];
      lf = cmul(lf, col);
    }
    F2 c01[4];
    #pragma unroll
    for (int dd = 0; dd < 4; ++dd)
      c01[dd] = cmul((dd & 1) ? sUpre[0][2] : sUpre[0][0],
                     (dd & 2) ? sUpre[1][2] : sUpre[1][0]);
    #pragma unroll
    for (int j = 0; j < 16; ++j)
      a[j] = (j >> 2) ? F2{0.f, 0.f} : cmul(lf, c01[j & 3]);
  } else {
    // load previous phase (256 amps, anc bits fresh |0>) + P1 {0,1,2,3}
    const F2* sp = src + ((L == 1) ? (b * 1024 + s * 256) : (b * 4096 + s * 256));
    #pragma unroll
    for (int j = 0; j < 16; ++j) {
      const int d = j | ((lane & 15) << 4);
      a[j] = (lane >> 4) ? F2{0.f, 0.f} : sp[d];
    }
    gate1(a, sUpre[0], 0); gate1(a, sUpre[1], 1);
    gate1(a, sUpre[2], 2); gate1(a, sUpre[3], 3);
    writeGrp<0x00Fu>(amp, lane, a);
    __syncthreads();
    // P2 {4,5,6,7}
    readGrp<0x0F0u>(amp, lane, a);
    gate1(a, sUpre[4], 0); gate1(a, sUpre[5], 1);
    gate1(a, sUpre[6], 2); gate1(a, sUpre[7], 3);
    writeGrp<0x0F0u>(amp, lane, a);
    __syncthreads();
    readGrp<0x303u>(amp, lane, a);
  }

  // ---- P3 {d0,d1,a0,a1}: H(anc), CRZ phases, (H(anc) if L odd), M4(0,1), CCRX(a0,0,1)
  gateH(a, 2); gateH(a, 3);
  {
    float base0 = 0.f, base1 = 0.f;
    #pragma unroll
    for (int t = 0; t < 6; ++t) {
      const float bit = (float)((lane >> t) & 1);
      base0 += bit * sPW[0][2 + t];
      base1 += bit * sPW[1][2 + t];
    }
    const float pw00 = sPW[0][0], pw01 = sPW[0][1];
    const float pw10 = sPW[1][0], pw11 = sPW[1][1];
    #pragma unroll
    for (int dd = 0; dd < 4; ++dd) {
      const float w0 = 0.5f * (base0 + (dd & 1) * pw00 + ((dd >> 1) & 1) * pw01);
      const float w1 = 0.5f * (base1 + (dd & 1) * pw10 + ((dd >> 1) & 1) * pw11);
      float c0, s0, c1, s1;
      __sincosf(w0, &s0, &c0);
      __sincosf(w1, &s1, &c1);
      #pragma unroll
      for (int aa = 0; aa < 4; ++aa) {
        F2 f0 = F2{ c0, (aa & 1) ? s0 : -s0 };
        F2 f1 = F2{ c1, (aa & 2) ? s1 : -s1 };
        const int j = dd | (aa << 2);
        a[j] = cmul(a[j], cmul(f0, f1));
      }
    }
  }
  if (L == 1) { gateH(a, 2); gateH(a, 3); }
  gateM4(a, sM4[0], 0, 1);     // pair (0,1)
  gateCCRX(a, 2, 0, 1);        // controls a0,d0 target d1
  writeGrp<0x303u>(amp, lane, a);
  __syncthreads();

  // ---- P4 {d1,d2,d3,a1}
  readGrp<0x20Eu>(amp, lane, a);
  gateM4(a, sM4[1], 1, 2);     // pair (2,3)
  gateCCRX(a, 3, 1, 2);        // controls a1,d2 target d3
  gateM4(a, sM4[4], 0, 1);     // off pair (1,2)
  writeGrp<0x20Eu>(amp, lane, a);
  __syncthreads();

  // ---- P5 {d4,d5,d6,d7}
  readGrp<0x0F0u>(amp, lane, a);
  gateM4(a, sM4[2], 0, 1);     // pair (4,5)
  gateM4(a, sM4[3], 2, 3);     // pair (6,7)
  writeGrp<0x0F0u>(amp, lane, a);
  __syncthreads();

  // ---- P6 {d3,d4,d5,d6}
  readGrp<0x078u>(amp, lane, a);
  gateM4(a, sM4[5], 0, 1);     // off pair (3,4)
  gateM4(a, sM4[6], 2, 3);     // off pair (5,6)
  if constexpr (L == 2) {
    gate1(a, sUpost[3], 0); gate1(a, sUpost[4], 1);
    gate1(a, sUpost[5], 2); gate1(a, sUpost[6], 3);
  }
  writeGrp<0x078u>(amp, lane, a);
  __syncthreads();

  if constexpr (L < 2) {
    // store canonical order; layer-1 scatter groups by its anc value so the
    // next phase reads a contiguous 256-amp block
    #pragma unroll
    for (int r = 0; r < 16; ++r) {
      const int i = r * 64 + lane;
      F2 v = amp[sw((uint32_t)i)];
      if (L == 0) dst[b * 1024 + i] = v;
      else        dst[b * 4096 + s * 256 + (i >> 8) * 1024 + (i & 255)] = v;
    }
  } else {
    // ---- P7 {d0,d1,d2,d7}: remaining U_post + measurement
    readGrp<0x087u>(amp, lane, a);
    gate1(a, sUpost[0], 0); gate1(a, sUpost[1], 1);
    gate1(a, sUpost[2], 2); gate1(a, sUpost[7], 3);
    float T = 0.f, E0 = 0.f, E1 = 0.f, E2 = 0.f, E7 = 0.f;
    #pragma unroll
    for (int j = 0; j < 16; ++j) {
      const float p = a[j].x * a[j].x + a[j].y * a[j].y;
      T += p;
      E0 += (j & 1) ? -p : p;
      E1 += (j & 2) ? -p : p;
      E2 += (j & 4) ? -p : p;
      E7 += (j & 8) ? -p : p;
    }
    float ev[8];
    ev[0] = E0; ev[1] = E1; ev[2] = E2; ev[7] = E7;
    ev[3] = ((lane >> 0) & 1) ? -T : T;   // d3..d6 are lane bits 0..3
    ev[4] = ((lane >> 1) & 1) ? -T : T;
    ev[5] = ((lane >> 2) & 1) ? -T : T;
    ev[6] = ((lane >> 3) & 1) ? -T : T;
    #pragma unroll
    for (int q = 0; q < 8; ++q) {
      float v = ev[q];
      #pragma unroll
      for (int k = 1; k < 64; k <<= 1) v += __shfl_xor(v, k, 64);
      if (lane == 0) atomicAdd(&out[b * 8 + q], v);
    }
  }
}

extern "C" void kernel_launch(void* const* d_in, const int* in_sizes, int n_in,
                              void* d_out, int out_size, void* d_ws, size_t ws_size,
                              hipStream_t stream) {
  (void)in_sizes; (void)n_in; (void)out_size; (void)ws_size;
  const float* x   = (const float*)d_in[0];   // (16,8)
  const float* w   = (const float*)d_in[1];   // (3,48)
  const float* pwg = (const float*)d_in[2];   // (3,2,8)
  float* out = (float*)d_out;                 // (16,8)
  F2* wsA = (F2*)d_ws;                        // 16*1024 amps (128 KB)
  F2* wsB = wsA + 16 * 1024;                  // 16*4096 amps (512 KB)

  qsim<0><<<16,  64, 0, stream>>>(x, w, pwg, nullptr, wsA, out);
  qsim<1><<<64,  64, 0, stream>>>(x, w, pwg, wsA,     wsB, out);
  qsim<2><<<256, 64, 0, stream>>>(x, w, pwg, wsB,  nullptr, out);
}

// Round 2
// 81.812 us; speedup vs baseline: 1.0497x; 1.0497x over previous
//
#include <hip/hip_runtime.h>
#include <cstdint>

// Fully-fused quantum circuit simulator (see round-0 notes for the math):
//  - SWAP(anc,rec) = wire relabel; layer L's live space = 1024 amps
//    {d0..d7, ancL0, ancL1}; spectator anc bits factor the state.
//  - Refinement tree: L2 chunk (b,s1,s2) <- L1 chunk (b,s1) <- L0 chunk b.
//    One wave per (b,s1,s2) recomputes its ancestors redundantly (a
//    chunk-unit ~3us is cheaper than a kernel launch gap), so the whole
//    circuit is ONE main kernel: 256 blocks x 64 threads, 8KB LDS scratch,
//    no workspace traffic, no inter-kernel dependencies.
//  - d_out is atomically accumulated (16 waves per batch element), so a
//    tiny zero-out kernel runs first on the same stream.

struct F2 { float x, y; };

__device__ __forceinline__ F2 cmul(F2 a, F2 b) {
  return F2{ a.x * b.x - a.y * b.y, a.x * b.y + a.y * b.x };
}
__device__ __forceinline__ F2 cfma2(F2 a, F2 b, F2 c) { // a*b + c
  return F2{ fmaf(a.x, b.x, fmaf(-a.y, b.y, c.x)),
             fmaf(a.x, b.y, fmaf( a.y, b.x, c.y)) };
}

// deposit bits of x into the set positions of compile-time MASK (low->high)
template<uint32_t MASK>
__device__ __forceinline__ uint32_t pdep10(uint32_t x) {
  uint32_t r = 0;
  #pragma unroll
  for (int b = 0; b < 10; ++b) {
    if (MASK & (1u << b)) { r |= (x & 1u) << b; x >>= 1; }
  }
  return r;
}

// LDS anti-bank-conflict swizzle
__device__ __forceinline__ uint32_t sw(uint32_t i) { return i ^ ((i >> 5) & 31u); }

template<uint32_t MASK>
__device__ __forceinline__ void readGrp(const F2* lds, int lane, F2 a[16]) {
  const uint32_t base = pdep10<(~MASK) & 0x3FFu>((uint32_t)lane);
  #pragma unroll
  for (uint32_t j = 0; j < 16; ++j) a[j] = lds[sw(base | pdep10<MASK>(j))];
}
template<uint32_t MASK>
__device__ __forceinline__ void writeGrp(F2* lds, int lane, const F2 a[16]) {
  const uint32_t base = pdep10<(~MASK) & 0x3FFu>((uint32_t)lane);
  #pragma unroll
  for (uint32_t j = 0; j < 16; ++j) lds[sw(base | pdep10<MASK>(j))] = a[j];
}

// single-qubit 2x2 on local bit p
__device__ __forceinline__ void gate1(F2 a[16], const F2 U[4], int p) {
  const int s = 1 << p;
  #pragma unroll
  for (int i = 0; i < 16; ++i) {
    if (i & s) continue;
    F2 a0 = a[i], a1 = a[i | s];
    a[i]     = cfma2(U[0], a0, cmul(U[1], a1));
    a[i | s] = cfma2(U[2], a0, cmul(U[3], a1));
  }
}

__device__ __forceinline__ void gateH(F2 a[16], int p) {
  const float R = 0.70710678118654752f;
  const int s = 1 << p;
  #pragma unroll
  for (int i = 0; i < 16; ++i) {
    if (i & s) continue;
    F2 a0 = a[i], a1 = a[i | s];
    a[i]     = F2{ (a0.x + a1.x) * R, (a0.y + a1.y) * R };
    a[i | s] = F2{ (a0.x - a1.x) * R, (a0.y - a1.y) * R };
  }
}

// fused RZZ*RYY*RXX: m = {alpha,beta,gamma,delta}
__device__ __forceinline__ void gateM4(F2 a[16], const F2 m[4], int p, int q) {
  const int sp = 1 << p, sq = 1 << q;
  #pragma unroll
  for (int i = 0; i < 16; ++i) {
    if (i & (sp | sq)) continue;
    F2 v0 = a[i], v1 = a[i | sq], v2 = a[i | sp], v3 = a[i | sp | sq];
    a[i]           = cfma2(m[0], v0, cmul(m[2], v3));
    a[i | sp | sq] = cfma2(m[2], v0, cmul(m[0], v3));
    a[i | sq]      = cfma2(m[1], v1, cmul(m[3], v2));
    a[i | sp]      = cfma2(m[3], v1, cmul(m[1], v2));
  }
}

// doubly-controlled RX(pi/4): controls c1,c2; target t
__device__ __forceinline__ void gateCCRX(F2 a[16], int c1, int c2, int t) {
  const float C = 0.92387953251128674f;  // cos(pi/8)
  const float S = 0.38268343236508978f;  // sin(pi/8)
  const int cm = (1 << c1) | (1 << c2);
  const int st = 1 << t;
  #pragma unroll
  for (int i = 0; i < 16; ++i) {
    if ((i & (cm | st)) != cm) continue;
    F2 a0 = a[i], a1 = a[i | st];
    a[i]      = F2{ fmaf(C, a0.x,  S * a1.y), fmaf(C, a0.y, -S * a1.x) };
    a[i | st] = F2{ fmaf(C, a1.x,  S * a0.y), fmaf(C, a1.y, -S * a0.x) };
  }
}

__device__ __forceinline__ void rot_rx(F2 m[4], float t) {
  float c, s; __sincosf(0.5f * t, &s, &c);
  m[0] = F2{c, 0.f}; m[1] = F2{0.f, -s}; m[2] = F2{0.f, -s}; m[3] = F2{c, 0.f};
}
__device__ __forceinline__ void rot_ry(F2 m[4], float t) {
  float c, s; __sincosf(0.5f * t, &s, &c);
  m[0] = F2{c, 0.f}; m[1] = F2{-s, 0.f}; m[2] = F2{s, 0.f}; m[3] = F2{c, 0.f};
}
__device__ __forceinline__ void rot_rz(F2 m[4], float t) {
  float c, s; __sincosf(0.5f * t, &s, &c);
  m[0] = F2{c, -s}; m[1] = F2{0.f, 0.f}; m[2] = F2{0.f, 0.f}; m[3] = F2{c, s};
}
__device__ __forceinline__ void mat2mul(F2 o[4], const F2 A[4], const F2 B[4]) {
  o[0] = cfma2(A[0], B[0], cmul(A[1], B[2]));
  o[1] = cfma2(A[0], B[1], cmul(A[1], B[3]));
  o[2] = cfma2(A[2], B[0], cmul(A[3], B[2]));
  o[3] = cfma2(A[2], B[1], cmul(A[3], B[3]));
}

// P3..P6 of one layer; on entry a[] holds the chunk in P3 grouping
// {d0,d1,a0,a1}; on exit amp[] holds the full 1024-amp chunk (sw-canonical).
template<int L>
__device__ __forceinline__ void layer_tail(F2 a[16], F2* amp, int lane,
    const F2 (*M4)[4], const float* PW0, const float* PW1,
    const F2 (*Upost)[4])
{
  // H on fresh ancillas, then all 16 CRZ phases in one pass
  gateH(a, 2); gateH(a, 3);
  {
    float base0 = 0.f, base1 = 0.f;
    #pragma unroll
    for (int t = 0; t < 6; ++t) {
      const float bit = (float)((lane >> t) & 1);
      base0 += bit * PW0[2 + t];
      base1 += bit * PW1[2 + t];
    }
    const float pw00 = PW0[0], pw01 = PW0[1];
    const float pw10 = PW1[0], pw11 = PW1[1];
    #pragma unroll
    for (int dd = 0; dd < 4; ++dd) {
      const float w0 = 0.5f * (base0 + (dd & 1) * pw00 + ((dd >> 1) & 1) * pw01);
      const float w1 = 0.5f * (base1 + (dd & 1) * pw10 + ((dd >> 1) & 1) * pw11);
      float c0, s0, c1, s1;
      __sincosf(w0, &s0, &c0);
      __sincosf(w1, &s1, &c1);
      #pragma unroll
      for (int aa = 0; aa < 4; ++aa) {
        F2 f0 = F2{ c0, (aa & 1) ? s0 : -s0 };
        F2 f1 = F2{ c1, (aa & 2) ? s1 : -s1 };
        const int j = dd | (aa << 2);
        a[j] = cmul(a[j], cmul(f0, f1));
      }
    }
  }
  if (L == 1) { gateH(a, 2); gateH(a, 3); }
  gateM4(a, M4[0], 0, 1);      // pair (0,1)
  gateCCRX(a, 2, 0, 1);        // controls a0,d0 target d1
  writeGrp<0x303u>(amp, lane, a);
  __syncthreads();

  // P4 {d1,d2,d3,a1}
  readGrp<0x20Eu>(amp, lane, a);
  gateM4(a, M4[1], 1, 2);      // pair (2,3)
  gateCCRX(a, 3, 1, 2);        // controls a1,d2 target d3
  gateM4(a, M4[4], 0, 1);      // off pair (1,2)
  writeGrp<0x20Eu>(amp, lane, a);
  __syncthreads();

  // P5 {d4,d5,d6,d7}
  readGrp<0x0F0u>(amp, lane, a);
  gateM4(a, M4[2], 0, 1);      // pair (4,5)
  gateM4(a, M4[3], 2, 3);      // pair (6,7)
  writeGrp<0x0F0u>(amp, lane, a);
  __syncthreads();

  // P6 {d3,d4,d5,d6}
  readGrp<0x078u>(amp, lane, a);
  gateM4(a, M4[5], 0, 1);      // off pair (3,4)
  gateM4(a, M4[6], 2, 3);      // off pair (5,6)
  if constexpr (L == 2) {
    gate1(a, Upost[3], 0); gate1(a, Upost[4], 1);
    gate1(a, Upost[5], 2); gate1(a, Upost[6], 3);
  }
  writeGrp<0x078u>(amp, lane, a);
  __syncthreads();
}

// P1,P2 of layer L (L>=1): a[] holds the 256-amp parent slice in P1
// grouping (reg bits = d0..d3, lane bits 0..3 = d4..d7, anc zero on
// lanes>=16). Ends with a[] in P3 grouping.
__device__ __forceinline__ void layer_head(F2 a[16], F2* amp, int lane,
                                           const F2 (*Upre)[4])
{
  gate1(a, Upre[0], 0); gate1(a, Upre[1], 1);
  gate1(a, Upre[2], 2); gate1(a, Upre[3], 3);
  writeGrp<0x00Fu>(amp, lane, a);
  __syncthreads();
  readGrp<0x0F0u>(amp, lane, a);
  gate1(a, Upre[4], 0); gate1(a, Upre[5], 1);
  gate1(a, Upre[6], 2); gate1(a, Upre[7], 3);
  writeGrp<0x0F0u>(amp, lane, a);
  __syncthreads();
  readGrp<0x303u>(amp, lane, a);
}

// extract 256-amp slice (anc value sel) of the chunk in amp[] into P1 grouping
__device__ __forceinline__ void extract_slice(const F2* amp, int lane, int sel,
                                              F2 a[16])
{
  #pragma unroll
  for (int j = 0; j < 16; ++j) {
    const int d = j | ((lane & 15) << 4);
    F2 v = amp[sw((uint32_t)(d | (sel << 8)))];
    a[j] = (lane >> 4) ? F2{0.f, 0.f} : v;
  }
  __syncthreads();  // slice fully read before amp is overwritten
}

__global__ __launch_bounds__(128) void zero_out_k(float* out) {
  out[threadIdx.x] = 0.f;
}

__global__ __launch_bounds__(64)
void qpie_fused(const float* __restrict__ x, const float* __restrict__ w,
                const float* __restrict__ pwg, float* __restrict__ out)
{
  __shared__ F2 amp[1024];
  __shared__ F2 sUpre[3][8][4];
  __shared__ F2 sUpost[8][4];
  __shared__ F2 sM4[3][7][4];
  __shared__ float sPW[3][2][8];

  const int lane = threadIdx.x;
  const int blk  = blockIdx.x;          // b*16 + s1*4 + s2
  const int b  = blk >> 4;
  const int s1 = (blk >> 2) & 3;
  const int s2 = blk & 3;

  // ---- all gate parameters for all 3 layers (single wave, lane-parallel)
  if (lane < 24) {
    const int Lp = lane >> 3, q = lane & 7;
    F2 tail[4];
    if (Lp == 0) {
      const float R = 0.70710678118654752f;
      tail[0] = F2{R, 0.f}; tail[1] = F2{R, 0.f};
      tail[2] = F2{R, 0.f}; tail[3] = F2{-R, 0.f};
    } else {
      F2 rx[4], ry[4], rz[4], t0[4];
      rot_rx(rx, w[(Lp - 1) * 48 + 24 + 3 * q]);
      rot_ry(ry, w[(Lp - 1) * 48 + 24 + 3 * q + 1]);
      rot_rz(rz, w[(Lp - 1) * 48 + 24 + 3 * q + 2]);
      mat2mul(t0, ry, rx);
      mat2mul(tail, rz, t0);
    }
    F2 rot[4];
    if ((Lp & 1) == 0) rot_ry(rot, x[b * 8 + q]); else rot_rx(rot, x[b * 8 + q]);
    F2 u[4]; mat2mul(u, rot, tail);
    #pragma unroll
    for (int k = 0; k < 4; ++k) sUpre[Lp][q][k] = u[k];
  } else if (lane < 45) {
    const int t = lane - 24;
    const int Lp = t / 7, p = t % 7;
    float cx, sx, cy, sy, cz, sz;
    __sincosf(0.5f * w[Lp * 48 + 3 * p    ], &sx, &cx);
    __sincosf(0.5f * w[Lp * 48 + 3 * p + 1], &sy, &cy);
    __sincosf(0.5f * w[Lp * 48 + 3 * p + 2], &sz, &cz);
    const F2 e  = F2{cz, -sz};
    const F2 eb = F2{cz,  sz};
    const float P = cx * cy + sx * sy, Q = cx * cy - sx * sy;
    sM4[Lp][p][0] = F2{ e.x * P,  e.y * P };
    sM4[Lp][p][1] = F2{ eb.x * Q, eb.y * Q };
    sM4[Lp][p][2] = cmul(e,  F2{0.f,  sy * cx - sx * cy});
    sM4[Lp][p][3] = cmul(eb, F2{0.f, -(sx * cy + sy * cx)});
  } else if (lane < 53) {
    const int q = lane - 45;
    F2 rx[4], ry[4], rz[4], t0[4], t1[4];
    rot_rx(rx, w[2 * 48 + 24 + 3 * q]);
    rot_ry(ry, w[2 * 48 + 24 + 3 * q + 1]);
    rot_rz(rz, w[2 * 48 + 24 + 3 * q + 2]);
    mat2mul(t0, ry, rx); mat2mul(t1, rz, t0);
    #pragma unroll
    for (int k = 0; k < 4; ++k) sUpost[q][k] = t1[k];
  } else if (lane >= 56) {
    const int k = lane - 56;
    float* pf = &sPW[0][0][0];
    #pragma unroll
    for (int m = 0; m < 6; ++m) pf[k * 6 + m] = pwg[k * 6 + m];
  }
  __syncthreads();

  F2 a[16];

  // ===== Layer 0: product state directly in P3 grouping {d0,d1,a0,a1} =====
  {
    F2 lf = F2{1.f, 0.f};
    #pragma unroll
    for (int t = 0; t < 6; ++t) {
      const int bit = (lane >> t) & 1;
      F2 col = bit ? sUpre[0][2 + t][2] : sUpre[0][2 + t][0];
      lf = cmul(lf, col);
    }
    F2 c01[4];
    #pragma unroll
    for (int dd = 0; dd < 4; ++dd)
      c01[dd] = cmul((dd & 1) ? sUpre[0][0][2] : sUpre[0][0][0],
                     (dd & 2) ? sUpre[0][1][2] : sUpre[0][1][0]);
    #pragma unroll
    for (int j = 0; j < 16; ++j)
      a[j] = (j >> 2) ? F2{0.f, 0.f} : cmul(lf, c01[j & 3]);
  }
  layer_tail<0>(a, amp, lane, sM4[0], sPW[0][0], sPW[0][1], sUpost);

  // ===== Layer 1 (slice s1 of the L0 chunk) =====
  extract_slice(amp, lane, s1, a);
  layer_head(a, amp, lane, sUpre[1]);
  layer_tail<1>(a, amp, lane, sM4[1], sPW[1][0], sPW[1][1], sUpost);

  // ===== Layer 2 (slice s2 of the L1 chunk) =====
  extract_slice(amp, lane, s2, a);
  layer_head(a, amp, lane, sUpre[2]);
  layer_tail<2>(a, amp, lane, sM4[2], sPW[2][0], sPW[2][1], sUpost);

  // ===== P7 {d0,d1,d2,d7}: remaining U_post + measurement =====
  readGrp<0x087u>(amp, lane, a);
  gate1(a, sUpost[0], 0); gate1(a, sUpost[1], 1);
  gate1(a, sUpost[2], 2); gate1(a, sUpost[7], 3);
  float T = 0.f, E0 = 0.f, E1 = 0.f, E2 = 0.f, E7 = 0.f;
  #pragma unroll
  for (int j = 0; j < 16; ++j) {
    const float p = a[j].x * a[j].x + a[j].y * a[j].y;
    T += p;
    E0 += (j & 1) ? -p : p;
    E1 += (j & 2) ? -p : p;
    E2 += (j & 4) ? -p : p;
    E7 += (j & 8) ? -p : p;
  }
  float ev[8];
  ev[0] = E0; ev[1] = E1; ev[2] = E2; ev[7] = E7;
  ev[3] = ((lane >> 0) & 1) ? -T : T;   // d3..d6 are lane bits 0..3
  ev[4] = ((lane >> 1) & 1) ? -T : T;
  ev[5] = ((lane >> 2) & 1) ? -T : T;
  ev[6] = ((lane >> 3) & 1) ? -T : T;
  #pragma unroll
  for (int q = 0; q < 8; ++q) {
    float v = ev[q];
    #pragma unroll
    for (int k = 1; k < 64; k <<= 1) v += __shfl_xor(v, k, 64);
    if (lane == 0) atomicAdd(&out[b * 8 + q], v);
  }
}

extern "C" void kernel_launch(void* const* d_in, const int* in_sizes, int n_in,
                              void* d_out, int out_size, void* d_ws, size_t ws_size,
                              hipStream_t stream) {
  (void)in_sizes; (void)n_in; (void)out_size; (void)d_ws; (void)ws_size;
  const float* x   = (const float*)d_in[0];   // (16,8)
  const float* w   = (const float*)d_in[1];   // (3,48)
  const float* pwg = (const float*)d_in[2];   // (3,2,8)
  float* out = (float*)d_out;                 // (16,8)

  zero_out_k<<<1, 128, 0, stream>>>(out);
  qpie_fused<<<256, 64, 0, stream>>>(x, w, pwg, out);
}